// Round 10
// baseline (120.911 us; speedup 1.0000x reference)
//
#include <hip/hip_runtime.h>

#define NB     20000
#define NL     320000
#define NOTH   1000
#define BATCH  128
#define ROW    (2*NB + NOTH)   // 41000
#define CAP    80              // events/bus capacity; degree ~ Poisson(32), max ~60
#define NBLK   256             // histo/place blocks
#define LSEG   (NL/NBLK)       // 1250 lines per block
#define PACKB  64              // extra histo-grid blocks that pack ldata
#define BCHUNK 4               // bus chunks (delta): 512 blocks, 2/CU
#define CB     (NB/BCHUNK)     // 5000 buses per block
#define NSLICE 2               // line slices (flows): 256 blocks
#define LPS    (NL/NSLICE)     // 160000 lines per slice
#define SCANB  40              // scan blocks
#define COPYB  256             // concurrent copy blocks in scancopy_k
#define CPF4   (BATCH*(NB/4 + NOTH/4))   // float4s to copy: 672000

typedef float vf4 __attribute__((ext_vector_type(4)));

__device__ __forceinline__ float fast_rcp(float a)
{
    float r;
    asm volatile("v_rcp_f32 %0, %1" : "=v"(r) : "v"(a));
    return r;
}

// ---------------------------------------------------------------------------
// Kernel 1: blocks 0..255 = per-segment LDS histogram -> u8 partials H.
// Blocks 256..319 = pack line data for flows: uint2 {f<<15|t, 1/xr} (8 B/line
// instead of 12 -> flows' 492 MB logical line reads become 328 MB).
// ---------------------------------------------------------------------------
__global__ __launch_bounds__(512) void histo_pack_k(
    const int* __restrict__ fidx, const int* __restrict__ tidx,
    const float* __restrict__ xr, uchar* __restrict__ H,
    uint2* __restrict__ ldata)
{
    if (blockIdx.x >= NBLK) {                          // ---- pack section ----
        const int gt = (blockIdx.x - NBLK) * 512 + (int)threadIdx.x;
        for (int l = gt; l < NL; l += PACKB * 512) {
            uint2 w;
            w.x = ((unsigned)fidx[l] << 15) | (unsigned)tidx[l];
            w.y = __float_as_uint(1.0f / xr[l]);       // full-precision rcp
            ldata[l] = w;
        }
        return;
    }
    extern __shared__ uint h[];                        // NB uints = 80 KB
    for (int i = threadIdx.x; i < NB; i += 512) h[i] = 0u;
    __syncthreads();

    const int l0 = blockIdx.x * LSEG;
    for (int l = l0 + (int)threadIdx.x; l < l0 + LSEG; l += 512) {
        atomicAdd(&h[fidx[l]], 1u);                    // LDS atomics, CU-local
        atomicAdd(&h[tidx[l]], 1u);
    }
    __syncthreads();

    uint* __restrict__ Hrow = (uint*)(H + (size_t)blockIdx.x * NB);
    for (int i = threadIdx.x; i < NB / 4; i += 512) {
        const uint c0 = min(h[4 * i + 0], 255u), c1 = min(h[4 * i + 1], 255u);
        const uint c2 = min(h[4 * i + 2], 255u), c3 = min(h[4 * i + 3], 255u);
        Hrow[i] = c0 | (c1 << 8) | (c2 << 16) | (c3 << 24);
    }
}

// ---------------------------------------------------------------------------
// Kernel 2: blocks 0..39 scan the 256 u8 partials per bus (in place, u8
// exclusive prefix; totals <= ~60) + emit cnt. Blocks 40..295 copy the
// voltages+other regions x->out concurrently (independent of the build).
// ---------------------------------------------------------------------------
__global__ __launch_bounds__(512) void scancopy_k(
    uchar* __restrict__ H, int* __restrict__ cnt,
    const float* __restrict__ x, float* __restrict__ out)
{
    if (blockIdx.x < SCANB) {
        const int u = blockIdx.x * 512 + (int)threadIdx.x;
        if (u >= NB) return;
        uint run = 0;
        for (int b = 0; b < NBLK; ++b) {
            const uint v = H[(size_t)b * NB + u];
            H[(size_t)b * NB + u] = (uchar)run;        // exclusive prefix
            run += v;
        }
        cnt[u] = (int)run;
    } else {
        const int nthr = COPYB * 512;
        int idx = (blockIdx.x - SCANB) * 512 + (int)threadIdx.x;
        for (; idx < CPF4; idx += nthr) {
            const int b = idx / (NB / 4 + NOTH / 4);
            const int r = idx % (NB / 4 + NOTH / 4);
            const int off = (r < NB / 4) ? r : (2 * NB / 4) + (r - NB / 4);
            const size_t p = (size_t)b * (ROW / 4) + off;
            ((float4*)out)[p] = ((const float4*)x)[p];
        }
    }
}

// ---------------------------------------------------------------------------
// Kernel 3: place events. slot = u8 global prefix (staged in LDS) + LDS rank.
// Event word: bits31:17 = other endpoint, bit16 = side, bits15:0 = bf16(rl).
// ---------------------------------------------------------------------------
__global__ __launch_bounds__(512) void place_k(
    const int* __restrict__ fidx, const int* __restrict__ tidx,
    const float* __restrict__ xr, const float* __restrict__ lim,
    const uchar* __restrict__ H, unsigned* __restrict__ bins)
{
    extern __shared__ char sm[];
    uint*  __restrict__ h    = (uint*)sm;              // NB uints = 80 KB
    uchar* __restrict__ pref = (uchar*)(sm + NB * 4);  // NB u8    = 20 KB

    const uchar* __restrict__ Hrow = H + (size_t)blockIdx.x * NB;
    for (int i = threadIdx.x; i < NB; i += 512) h[i] = 0u;
    for (int i = threadIdx.x; i < NB / 16; i += 512)
        ((uint4*)pref)[i] = ((const uint4*)Hrow)[i];
    __syncthreads();

    const int l0 = blockIdx.x * LSEG;
    for (int l = l0 + (int)threadIdx.x; l < l0 + LSEG; l += 512) {
        const int fi = fidx[l];
        const int ti = tidx[l];
        union { float f; unsigned u; } c; c.f = xr[l] * lim[l];
        const unsigned rl16 = (c.u + 0x8000u) >> 16;

        const uint s0 = (uint)pref[fi] + atomicAdd(&h[fi], 1u);
        if (s0 < CAP) bins[(size_t)s0 * NB + fi] = ((unsigned)ti << 17) | rl16;
        const uint s1 = (uint)pref[ti] + atomicAdd(&h[ti], 1u);
        if (s1 < CAP) bins[(size_t)s1 * NB + ti] =
            ((unsigned)fi << 17) | (1u << 16) | rl16;
    }
}

// ---------------------------------------------------------------------------
// Kernel 4: atomic-free delta (pure gather). BCHUNK=4 -> 512 blocks (2/CU),
// halves the angle-staging traffic vs BCHUNK=8.
// ---------------------------------------------------------------------------
__global__ __launch_bounds__(1024) void delta_k(
    const float* __restrict__ x, const int* __restrict__ cnt,
    const unsigned* __restrict__ bins, float* __restrict__ out)
{
    extern __shared__ float a[];                       // NB f32 = 80 KB
    const int b  = blockIdx.x % BATCH;                 // XCD = b%8
    const int cb = blockIdx.x / BATCH;

    const float* __restrict__ xrow = x   + (size_t)b * ROW;
    float*       __restrict__ orow = out + (size_t)b * ROW;

    for (int i = threadIdx.x; i < NB / 4; i += 1024)
        ((float4*)a)[i] = ((const float4*)(xrow + NB))[i];
    __syncthreads();

    const int base = cb * CB;
    for (int bus = base + (int)threadIdx.x; bus < base + CB; bus += 1024) {
        const int   n  = min(cnt[bus], CAP);
        const float ab = a[bus];
        float ds = 0.0f;
        int k = 0;
        #define CONTRIB(W)                                                   \
        {                                                                    \
            const unsigned w  = (W);                                         \
            const int   other = (int)(w >> 17);                              \
            const float rl    = __uint_as_float((w & 0xFFFFu) << 16);        \
            const float ad    = ab - a[other];                               \
            if (fabsf(ad) > rl) {                                            \
                float hh = 0.5f * (copysignf(rl, ad) - ad);                  \
                if (w & (1u << 16)) hh = -hh;                                \
                ds += hh;                                                    \
            }                                                                \
        }
        for (; k + 4 <= n; k += 4) {
            const unsigned w0 = bins[(size_t)(k + 0) * NB + bus];
            const unsigned w1 = bins[(size_t)(k + 1) * NB + bus];
            const unsigned w2 = bins[(size_t)(k + 2) * NB + bus];
            const unsigned w3 = bins[(size_t)(k + 3) * NB + bus];
            CONTRIB(w0) CONTRIB(w1) CONTRIB(w2) CONTRIB(w3)
        }
        for (; k < n; ++k) CONTRIB(bins[(size_t)k * NB + bus])
        #undef CONTRIB
        orow[NB + bus] = ab + ds;
    }
}

// ---------------------------------------------------------------------------
// Kernel 5: flows2 from packed ldata (8 B/line). angles2 staged f32 in LDS;
// 4 lines per thread-iter (2 uint4 loads -> 1 nt float4 store).
// ---------------------------------------------------------------------------
__global__ __launch_bounds__(1024) void flows_k(
    const float* __restrict__ out, const uint2* __restrict__ ldata,
    float* __restrict__ f2)
{
    extern __shared__ float a2[];                      // NB f32 = 80 KB
    const int b = blockIdx.x % BATCH;
    const int s = blockIdx.x / BATCH;

    const float* __restrict__ src = out + (size_t)b * ROW + NB;
    for (int i = threadIdx.x; i < NB / 4; i += 1024)
        ((float4*)a2)[i] = ((const float4*)src)[i];
    __syncthreads();

    float* __restrict__ frow = f2 + (size_t)b * NL;
    const int q0 = s * (LPS / 4);
    const int q1 = q0 + (LPS / 4);
    for (int q = q0 + (int)threadIdx.x; q < q1; q += 1024) {
        const uint4 p0 = ((const uint4*)ldata)[2 * q];      // lines 4q,4q+1
        const uint4 p1 = ((const uint4*)ldata)[2 * q + 1];  // lines 4q+2,4q+3
        vf4 o;
        o.x = (a2[p0.x >> 15] - a2[p0.x & 0x7FFFu]) * __uint_as_float(p0.y);
        o.y = (a2[p0.z >> 15] - a2[p0.z & 0x7FFFu]) * __uint_as_float(p0.w);
        o.z = (a2[p1.x >> 15] - a2[p1.x & 0x7FFFu]) * __uint_as_float(p1.y);
        o.w = (a2[p1.z >> 15] - a2[p1.z & 0x7FFFu]) * __uint_as_float(p1.w);
        __builtin_nontemporal_store(o, &((vf4*)frow)[q]);
    }
}

extern "C" void kernel_launch(void* const* d_in, const int* in_sizes, int n_in,
                              void* d_out, int out_size, void* d_ws, size_t ws_size,
                              hipStream_t stream)
{
    const float* x   = (const float*)d_in[0];
    const int*   fi  = (const int*)  d_in[1];
    const int*   ti  = (const int*)  d_in[2];
    const float* xr  = (const float*)d_in[3];
    const float* lim = (const float*)d_in[4];

    float* out    = (float*)d_out;                      // (128, 41000)
    float* flows2 = out + (size_t)BATCH * ROW;          // (128, 320000)

    // ws layout: H u8 (5.12 MB) | cnt int (80 KB) | bins u32 (6.4 MB) | ldata uint2 (2.56 MB)
    uchar*    H     = (uchar*)d_ws;
    int*      cnt   = (int*)((char*)d_ws + (size_t)NBLK * NB);
    unsigned* bins  = (unsigned*)((char*)cnt + (size_t)NB * 4);
    uint2*    ldata = (uint2*)((char*)bins + (size_t)CAP * NB * 4);

    histo_pack_k<<<dim3(NBLK + PACKB), dim3(512), NB * sizeof(uint), stream>>>(
        fi, ti, xr, H, ldata);

    scancopy_k<<<dim3(SCANB + COPYB), dim3(512), 0, stream>>>(H, cnt, x, out);

    place_k<<<dim3(NBLK), dim3(512), NB * 4 + NB, stream>>>(
        fi, ti, xr, lim, H, bins);

    delta_k<<<dim3(BCHUNK * BATCH), dim3(1024), NB * sizeof(float), stream>>>(
        x, cnt, bins, out);

    flows_k<<<dim3(NSLICE * BATCH), dim3(1024), NB * sizeof(float), stream>>>(
        out, ldata, flows2);
}